// Round 10
// baseline (362.049 us; speedup 1.0000x reference)
//
#include <hip/hip_runtime.h>

#define NB 32      // batch
#define NJ 8192    // h*w*Nin
#define NC 10      // NUM_CAPS
#define CL 16      // CAP_LEN
#define KK 160     // NC*CL
#define JT 16      // j per block
#define NTHR 640   // 40 k4 x 16 jj  (t = k4*16 + jj)
#define BB 16      // batches per block (2 b-groups)
#define BCH 4      // batches per barrier pair
#define NPART (NJ / JT)   // 512 partial slots along j
#define EPSQ 1e-20f

// in-wave sum over jj = lane&15, pure VALU via DPP adds
template<int CTRL>
__device__ __forceinline__ float dpp_add(float v) {
    int s = __builtin_amdgcn_update_dpp(0, __float_as_int(v), CTRL, 0xF, 0xF, true);
    return v + __int_as_float(s);
}
__device__ __forceinline__ float red16(float v) {
    v = dpp_add<0xB1>(v);    // quad_perm xor1
    v = dpp_add<0x4E>(v);    // quad_perm xor2
    v = dpp_add<0x141>(v);   // row_half_mirror
    v = dpp_add<0x140>(v);   // row_mirror
    return v;
}

// One routing iteration. W in registers (32 VGPR), u in registers,
// j-reduce via DPP, partials stored (no global atomics).
// b-split 2x for wave residency; XCD-pair swizzle keeps the two blocks
// sharing a W-slice on the SAME XCD, 8 dispatch slots apart -> L2 hit.
// Linearity trick: logits b_r[b,j,n] = u . (v0+...+v_{r-1}) -> carry only vsum.
template<int R>
__global__ __launch_bounds__(NTHR, 8)
void rout_kernel(const float* __restrict__ x, const float* __restrict__ W,
                 const float* __restrict__ vsum, float* __restrict__ part) {
    __shared__ float xs[BB][JT][10];   // 10 KB, pad -> b64 reads conflict-free
    __shared__ float bl[BCH][JT][12];  // 3 KB
    __shared__ float cl[BCH][JT][12];  // 3 KB

    const int t   = threadIdx.x;
    const int jj  = t & 15;            // j within tile
    const int k4  = t >> 4;            // float4 chunk of k, 0..39
    const int nB  = k4 >> 2;           // cap index
    const int c4  = k4 & 3;            // c-quad within cap (lane bits 4,5)

    // ---- XCD-pair swizzle: pair (h=0,1) differs by 8 in bid -> same XCD ----
    const int bid = blockIdx.x;                       // 0..1023
    const int jx  = ((bid >> 4) << 3) | (bid & 7);    // 0..511
    const int bof = ((bid >> 3) & 1) * BB;            // 0 or 16
    const int j0  = jx * JT;

    // ---- W -> registers, once (proven 32-VGPR layout) ----
    float4 w[8];
    {
        const float* wp = W + ((size_t)(j0 + jj) * 8) * KK + (k4 << 2);
        #pragma unroll
        for (int i = 0; i < 8; ++i)
            w[i] = *(const float4*)(wp + i * KK);
    }
    // ---- x tile (BB batches) -> LDS ----
    for (int e4 = t; e4 < BB * JT * 2; e4 += NTHR) {
        const int bb = e4 >> 5, rem = e4 & 31, jr = rem >> 1, hf = rem & 1;
        const float4 v = *(const float4*)(x + ((size_t)(bof + bb) * NJ + j0 + jr) * 8 + hf * 4);
        float* d = &xs[bb][jr][hf * 4];
        d[0] = v.x; d[1] = v.y; d[2] = v.z; d[3] = v.w;
    }
    __syncthreads();

    for (int b0 = 0; b0 < BB; b0 += BCH) {
        // ---- A: u quads in registers ----
        float4 u[BCH];
        #pragma unroll
        for (int bc = 0; bc < BCH; ++bc) {
            float4 acc = {0.f, 0.f, 0.f, 0.f};
            #pragma unroll
            for (int seg = 0; seg < 4; ++seg) {
                const float2 xv = *(const float2*)&xs[b0 + bc][jj][seg * 2];
                const float4 wa = w[seg * 2], wb = w[seg * 2 + 1];
                acc.x = fmaf(wa.x, xv.x, acc.x); acc.y = fmaf(wa.y, xv.x, acc.y);
                acc.z = fmaf(wa.z, xv.x, acc.z); acc.w = fmaf(wa.w, xv.x, acc.w);
                acc.x = fmaf(wb.x, xv.y, acc.x); acc.y = fmaf(wb.y, xv.y, acc.y);
                acc.z = fmaf(wb.z, xv.y, acc.z); acc.w = fmaf(wb.w, xv.y, acc.w);
            }
            u[bc] = acc;
        }

        if (R > 0) {
            // ---- B: logit = u . vsum (global read: L1/L2-hot,
            //         16-lane-uniform f4), reduce over c4 ----
            #pragma unroll
            for (int bc = 0; bc < BCH; ++bc) {
                const int b = bof + b0 + bc;
                const float4 vv = *(const float4*)(vsum + (size_t)b * KK + (k4 << 2));
                float bd = u[bc].x * vv.x + u[bc].y * vv.y
                         + u[bc].z * vv.z + u[bc].w * vv.w;
                bd += __shfl_xor(bd, 16);
                bd += __shfl_xor(bd, 32);
                if (c4 == 0) bl[bc][jj][nB] = bd;
            }
            __syncthreads();
            // ---- C: softmax over n, 640 = 4bc x 16jj x 10nn threads ----
            {
                const int bcC = t / 160, rem = t % 160;
                const int jjC = rem & 15, nn = rem >> 4;
                float m = -1e30f;
                #pragma unroll
                for (int q = 0; q < NC; ++q) m = fmaxf(m, bl[bcC][jjC][q]);
                float sum = 0.f;
                #pragma unroll
                for (int q = 0; q < NC; ++q) sum += __expf(bl[bcC][jjC][q] - m);
                cl[bcC][jjC][nn] = __expf(bl[bcC][jjC][nn] - m) / sum;
            }
            __syncthreads();
        }

        // ---- D: s partial = sum_jj c*u via DPP, one f4 store per (b,k4) ----
        #pragma unroll
        for (int bc = 0; bc < BCH; ++bc) {
            const int b = bof + b0 + bc;
            const float c = (R == 0) ? 0.1f : cl[bc][jj][nB];
            const float sx = red16(u[bc].x * c);
            const float sy = red16(u[bc].y * c);
            const float sz = red16(u[bc].z * c);
            const float sw = red16(u[bc].w * c);
            if (jj == 0) {
                float4 q; q.x = sx; q.y = sy; q.z = sz; q.w = sw;
                *(float4*)(part + ((size_t)jx * NB + b) * KK + (k4 << 2)) = q;
            }
        }
    }
}

// Sum NPART partials (coalesced), +bias, squash.
// MODE: 0 vsum=v, 1 vsum+=v, 2 out=v. Grid: 20 blocks x 1024 threads.
template<int MODE>
__global__ __launch_bounds__(1024)
void reduce_squash(const float* __restrict__ part, const float* __restrict__ biases,
                   float* __restrict__ vsum, float* __restrict__ out) {
    __shared__ float4 red[16][64];     // 16 KB
    const int t   = threadIdx.x;
    const int col = t & 63;
    const int pc  = t >> 6;
    const int g   = blockIdx.x * 64 + col;   // global f4 index, 0..1279
    const float4* p4 = (const float4*)part;

    float4 acc = {0.f, 0.f, 0.f, 0.f};
    #pragma unroll 4
    for (int p = pc * 32; p < pc * 32 + 32; ++p) {
        const float4 v = p4[(size_t)p * (NB * KK / 4) + g];
        acc.x += v.x; acc.y += v.y; acc.z += v.z; acc.w += v.w;
    }
    red[pc][col] = acc;
    __syncthreads();
    if (pc == 0) {
        #pragma unroll
        for (int q = 1; q < 16; ++q) {
            const float4 v = red[q][col];
            acc.x += v.x; acc.y += v.y; acc.z += v.z; acc.w += v.w;
        }
        const int k4 = g % 40;
        const float4 bb = *(const float4*)(biases + k4 * 4);
        float4 v;
        {
            const float s0 = acc.x + bb.x, n0 = fabsf(s0);
            v.x = (n0 * n0) / (1.f + n0 * n0) / (n0 + EPSQ) * s0;
            const float s1 = acc.y + bb.y, n1 = fabsf(s1);
            v.y = (n1 * n1) / (1.f + n1 * n1) / (n1 + EPSQ) * s1;
            const float s2 = acc.z + bb.z, n2 = fabsf(s2);
            v.z = (n2 * n2) / (1.f + n2 * n2) / (n2 + EPSQ) * s2;
            const float s3 = acc.w + bb.w, n3 = fabsf(s3);
            v.w = (n3 * n3) / (1.f + n3 * n3) / (n3 + EPSQ) * s3;
        }
        if (MODE == 2) {
            ((float4*)out)[g] = v;
        } else if (MODE == 1) {
            float4 o = ((float4*)vsum)[g];
            o.x += v.x; o.y += v.y; o.z += v.z; o.w += v.w;
            ((float4*)vsum)[g] = o;
        } else {
            ((float4*)vsum)[g] = v;
        }
    }
}

extern "C" void kernel_launch(void* const* d_in, const int* in_sizes, int n_in,
                              void* d_out, int out_size, void* d_ws, size_t ws_size,
                              hipStream_t stream) {
    const float* x      = (const float*)d_in[0];
    const float* W      = (const float*)d_in[1];
    const float* biases = (const float*)d_in[2];
    float* out  = (float*)d_out;
    float* part = (float*)d_ws;                        // [NPART][NB*KK]
    float* vsum = part + (size_t)NPART * NB * KK;      // [NB*KK]

    const dim3 grid(NJ / JT * (NB / BB));   // 1024 blocks, swizzled in-kernel

    rout_kernel<0><<<grid, NTHR, 0, stream>>>(x, W, nullptr, part);
    reduce_squash<0><<<20, 1024, 0, stream>>>(part, biases, vsum, out);

    rout_kernel<1><<<grid, NTHR, 0, stream>>>(x, W, vsum, part);
    reduce_squash<1><<<20, 1024, 0, stream>>>(part, biases, vsum, out);

    rout_kernel<2><<<grid, NTHR, 0, stream>>>(x, W, vsum, part);
    reduce_squash<2><<<20, 1024, 0, stream>>>(part, biases, vsum, out);
}